// Round 4
// baseline (356.132 us; speedup 1.0000x reference)
//
#include <hip/hip_runtime.h>

#define BATCH   8192
#define SEQ     50
#define DIM     128
#define NPROTO  16
#define NUSERS  100000
#define ROWF4   (NPROTO * DIM / 4)   // 512 vf4 per prototype row-set
#define DF4     (DIM / 4)            // 32 vf4 per embedding

typedef float vf4 __attribute__((ext_vector_type(4)));

// ---------------- Kernel 1: inv[u] = -1  AND  out_count[u] = icount[u] --------------------------
__global__ void k_init(const float* __restrict__ icount, int* __restrict__ inv,
                       float* __restrict__ out_count) {
    int i = blockIdx.x * blockDim.x + threadIdx.x;
    if (i < NUSERS) {
        inv[i] = -1;
        out_count[i] = icount[i];
    }
}

// ---------------- Kernel 2: inv[idx[b]] = b  AND  out_count[idx[b]] += 1 ------------------------
__global__ void k_prep(const int* __restrict__ idx, int* __restrict__ inv,
                       float* __restrict__ out_count) {
    int b = blockIdx.x * blockDim.x + threadIdx.x;
    if (b >= BATCH) return;
    int u = idx[b];
    inv[u] = b;
    atomicAdd(&out_count[u], 1.0f);
}

// ---------------- Kernel 3: MEGA ----------------------------------------------------------------
// Blocks [0, BATCH): batch row b — inline upd compute + gather + blend + scatter.
// Blocks [BATCH, BATCH+NUSERS): user row u — nontemporal copy unless row is in batch.
__global__ void __launch_bounds__(256) k_mega(
        const int* __restrict__ idx, const int* __restrict__ inv,
        const float* __restrict__ icount,
        const float* __restrict__ feat, const float* __restrict__ mask,
        const vf4* __restrict__ userP, const vf4* __restrict__ sharedP,
        float* __restrict__ upd,
        vf4* __restrict__ out1, vf4* __restrict__ out2, vf4* __restrict__ out3) {
    int bid = blockIdx.x;
    int t = threadIdx.x;

    if (bid >= BATCH) {
        int u = bid - BATCH;
        if (inv[u] >= 0) return;                 // batch block owns this row
        size_t base = (size_t)u * ROWF4;
        #pragma unroll
        for (int k = 0; k < 2; ++k) {
            int i = t + k * 256;
            vf4 v = __builtin_nontemporal_load(&userP[base + i]);
            __builtin_nontemporal_store(v, &out3[base + i]);
        }
        return;
    }

    // ---- batch path ----
    int b = bid;
    int u = idx[b];

    __shared__ vf4  lds_acc[8][32];
    __shared__ float lds_m[8];
    __shared__ vf4  lds_upd[32];

    // inline upd: 8 s-groups x 32 vf4 columns
    int l = t & 31;          // vf4 column
    int g = t >> 5;          // s-group
    const vf4* f4p = (const vf4*)(feat + (size_t)b * SEQ * DIM);
    const float* mk = mask + (size_t)b * SEQ;
    vf4 acc = {0.f, 0.f, 0.f, 0.f};
    float msum = 0.f;
    for (int s = g; s < SEQ; s += 8) {
        float m = mk[s];
        acc += __builtin_nontemporal_load(&f4p[s * DF4 + l]) * m;
        msum += m;
    }
    lds_acc[g][l] = acc;
    if (l == 0) lds_m[g] = msum;
    __syncthreads();
    if (t < 32) {
        vf4 a = lds_acc[0][t];
        #pragma unroll
        for (int gg = 1; gg < 8; ++gg) a += lds_acc[gg][t];
        float ms = lds_m[0];
        #pragma unroll
        for (int gg = 1; gg < 8; ++gg) ms += lds_m[gg];
        a *= 1.0f / fmaxf(ms, 1e-6f);
        float sq = a.x*a.x + a.y*a.y + a.z*a.z + a.w*a.w;
        for (int off = 16; off >= 1; off >>= 1)
            sq += __shfl_xor(sq, off, 32);
        a *= 1.0f / fmaxf(sqrtf(sq), 1e-12f);
        lds_upd[t] = a;
        ((vf4*)(upd + (size_t)b * DIM))[t] = a;   // for shared-proto mean
    }
    __syncthreads();

    float cnt = icount[u];                        // uniform scalar load
    float w = 1.0f / (1.0f + expf(3.0f - cnt * 0.01f));
    float m = fminf(fmaxf(0.9f + cnt * 0.001f, 0.9f), 0.99f);
    float w1 = 1.0f - w, m1 = 1.0f - m;
    size_t base = (size_t)u * ROWF4;
    size_t ob   = (size_t)b * ROWF4;
    #pragma unroll
    for (int k = 0; k < 2; ++k) {
        int i = t + k * 256;
        vf4 p  = __builtin_nontemporal_load(&userP[base + i]);
        vf4 sh = sharedP[i];
        vf4 ud = lds_upd[i & (DF4 - 1)];
        vf4 c  = w * p + w1 * sh;
        vf4 nr = m * p + m1 * ud;
        __builtin_nontemporal_store(c,  &out1[ob + i]);
        __builtin_nontemporal_store(nr, &out2[ob + i]);
        __builtin_nontemporal_store(nr, &out3[base + i]);
    }
}

// ---------------- Kernel 4: partial sums of upd over batch (deterministic) ----------------------
__global__ void k_partial(const float* __restrict__ upd, float* __restrict__ part) {
    int d = threadIdx.x;      // 0..127
    int j = blockIdx.x;       // 0..127
    float acc = 0.f;
    for (int b = j; b < BATCH; b += 128)
        acc += upd[(size_t)b * DIM + d];
    part[j * DIM + d] = acc;
}

// ---------------- Kernel 5: finalize new_shared -------------------------------------------------
__global__ void k_shared(const float* __restrict__ part, const float* __restrict__ sharedP,
                         float* __restrict__ out4) {
    __shared__ float red[DIM];
    int d = threadIdx.x;      // 0..127
    float s = 0.f;
    for (int j = 0; j < 128; ++j) s += part[j * DIM + d];
    float mean = s * (1.0f / (float)BATCH);
    red[d] = mean * mean;
    __syncthreads();
    for (int off = 64; off >= 1; off >>= 1) {
        if (d < off) red[d] += red[d + off];
        __syncthreads();
    }
    float normed = mean / fmaxf(sqrtf(red[0]), 1e-12f);
    for (int p = 0; p < NPROTO; ++p)
        out4[p * DIM + d] = 0.9f * sharedP[p * DIM + d] + 0.1f * normed;
}

extern "C" void kernel_launch(void* const* d_in, const int* in_sizes, int n_in,
                              void* d_out, int out_size, void* d_ws, size_t ws_size,
                              hipStream_t stream) {
    const int*   user_idx = (const int*)d_in[0];
    const float* features = (const float*)d_in[1];
    const float* smask    = (const float*)d_in[2];
    const float* userP    = (const float*)d_in[3];
    const float* sharedP  = (const float*)d_in[4];
    const float* icount   = (const float*)d_in[5];

    float* out = (float*)d_out;
    const size_t n1 = (size_t)BATCH * NPROTO * DIM;
    const size_t n3 = (size_t)NUSERS * NPROTO * DIM;
    float* out_combined = out;
    float* out_newrows  = out + n1;
    float* out_newproto = out + 2 * n1;
    float* out_shared   = out + 2 * n1 + n3;
    float* out_count    = out_shared + (size_t)NPROTO * DIM;

    float* ws_upd  = (float*)d_ws;                       // [B][D]   4 MB
    float* ws_part = ws_upd + (size_t)BATCH * DIM;       // [128][D] 64 KB
    int*   ws_inv  = (int*)(ws_part + 128 * DIM);        // [U]      400 KB

    k_init<<<(NUSERS + 255) / 256, 256, 0, stream>>>(icount, ws_inv, out_count);
    k_prep<<<(BATCH + 255) / 256, 256, 0, stream>>>(user_idx, ws_inv, out_count);
    k_mega<<<BATCH + NUSERS, 256, 0, stream>>>(user_idx, ws_inv, icount,
                                               features, smask,
                                               (const vf4*)userP, (const vf4*)sharedP,
                                               ws_upd,
                                               (vf4*)out_combined, (vf4*)out_newrows,
                                               (vf4*)out_newproto);
    k_partial<<<128, 128, 0, stream>>>(ws_upd, ws_part);
    k_shared<<<1, 128, 0, stream>>>(ws_part, sharedP, out_shared);
}